// Round 1
// baseline (1606.525 us; speedup 1.0000x reference)
//
#include <hip/hip_runtime.h>
#include <math.h>

#define NH   16
#define NKV  4
#define HD   64
#define B_   2
#define T_   2048
#define C_   1024

// ---------------- helpers ----------------
__device__ inline float lane_bcast(float x, int l) {
    return __int_as_float(__builtin_amdgcn_readlane(__float_as_int(x), l));
}
__device__ inline float wave_max64(float x) {
    #pragma unroll
    for (int o = 32; o; o >>= 1) x = fmaxf(x, __shfl_xor(x, o, 64));
    return x;
}
__device__ inline float wave_sum64(float x) {
    #pragma unroll
    for (int o = 32; o; o >>= 1) x += __shfl_xor(x, o, 64);
    return x;
}

// ---------------- fp32 tiled GEMM: C[M,N] = A[M,K] @ B[K,N] ----------------
// 64x64 tile, K-slab 16, 256 threads, 4x4 microtile.
// Requires M%64==0, N%64==0, K%16==0 (true for all our shapes).
__global__ __launch_bounds__(256) void gemm_f32(
    const float* __restrict__ A, const float* __restrict__ Bm,
    float* __restrict__ C, int M, int N, int K)
{
    __shared__ __align__(16) float As[16][68];  // [k][m], pad 4 keeps float4 align
    __shared__ __align__(16) float Bs[16][68];  // [k][n]

    const int tid = threadIdx.x;
    const int tx = tid & 15;        // n direction (16)
    const int ty = tid >> 4;        // m direction (16)
    const int m0 = blockIdx.y * 64;
    const int n0 = blockIdx.x * 64;

    float acc[4][4] = {};

    for (int k0 = 0; k0 < K; k0 += 16) {
        // Stage A: 64 rows x 16 k. One float4 per thread.
        {
            int m   = tid >> 2;         // 0..63
            int kk4 = (tid & 3) << 2;   // 0,4,8,12
            const float4 a4 = *(const float4*)(A + (size_t)(m0 + m) * K + k0 + kk4);
            As[kk4 + 0][m] = a4.x; As[kk4 + 1][m] = a4.y;
            As[kk4 + 2][m] = a4.z; As[kk4 + 3][m] = a4.w;
        }
        // Stage B: 16 k x 64 n. One float4 per thread, coalesced.
        {
            int kk = tid >> 4;          // 0..15
            int n4 = (tid & 15) << 2;   // 0..60
            *(float4*)&Bs[kk][n4] = *(const float4*)(Bm + (size_t)(k0 + kk) * N + n0 + n4);
        }
        __syncthreads();

        #pragma unroll
        for (int kk = 0; kk < 16; ++kk) {
            const float4 a = *(const float4*)&As[kk][ty << 2];
            const float4 b = *(const float4*)&Bs[kk][tx << 2];
            const float av[4] = {a.x, a.y, a.z, a.w};
            const float bv[4] = {b.x, b.y, b.z, b.w};
            #pragma unroll
            for (int i = 0; i < 4; ++i)
                #pragma unroll
                for (int j = 0; j < 4; ++j)
                    acc[i][j] += av[i] * bv[j];
        }
        __syncthreads();
    }

    #pragma unroll
    for (int i = 0; i < 4; ++i) {
        float4 r = {acc[i][0], acc[i][1], acc[i][2], acc[i][3]};
        *(float4*)(C + (size_t)(m0 + (ty << 2) + i) * N + n0 + (tx << 2)) = r;
    }
}

// ---------------- RoPE (in-place), layout [B*T, nh, 64] ----------------
__global__ __launch_bounds__(256) void rope_kernel(
    float* __restrict__ p, const float* __restrict__ cs,
    const float* __restrict__ sn, int nh, int total)
{
    int i = blockIdx.x * 256 + threadIdx.x;
    if (i >= total) return;
    int d   = i & 31;
    int hh  = (i >> 5) % nh;
    int row = i / (32 * nh);     // b*T + t
    int t   = row % T_;
    size_t base = (size_t)row * nh * HD + hh * HD + d;
    float x1 = p[base], x2 = p[base + 32];
    float c = cs[t * 32 + d], s = sn[t * 32 + d];
    p[base]      = x1 * c - x2 * s;
    p[base + 32] = x2 * c + x1 * s;
}

// ---------------- causal GQA attention ----------------
// q: [B*T, NH, 64]  k,v: [B*T, NKV, 64]  y: [B*T, NH, 64]
// Block = 256 threads = 4 waves; block covers 32 consecutive query rows of
// one (b,h); each wave owns 8 rows. Keys processed in chunks of 64 staged
// into LDS (K transposed, pad 65). Online softmax; lane-distributed q/p
// broadcast via v_readlane.
__global__ __launch_bounds__(256) void attn_kernel(
    const float* __restrict__ q, const float* __restrict__ k,
    const float* __restrict__ v, float* __restrict__ y)
{
    __shared__ __align__(16) float Kt[64][65];  // [d][j]
    __shared__ __align__(16) float Vt[64][64];  // [j][d]

    const int tid  = threadIdx.x;
    const int wave = tid >> 6;
    const int lane = tid & 63;

    const int tpb = T_ / 32;                 // 64 blocks per (b,h)
    const int blk = blockIdx.x;
    const int b   = blk / (NH * tpb);
    const int rem = blk % (NH * tpb);
    const int h   = rem / tpb;
    const int tb  = rem % tpb;
    const int base = tb * 32;
    const int kvh  = h >> 2;                 // N_GROUPS = 4
    const float scale = 0.125f;              // 1/sqrt(64)

    const float* kb = k + (size_t)b * T_ * NKV * HD + kvh * HD;
    const float* vb = v + (size_t)b * T_ * NKV * HD + kvh * HD;

    float qreg[8], o[8], m[8], l[8];
    int   trow[8];
    #pragma unroll
    for (int r = 0; r < 8; ++r) {
        trow[r] = base + wave * 8 + r;
        qreg[r] = q[((size_t)(b * T_ + trow[r]) * NH + h) * HD + lane];
        o[r] = 0.f; m[r] = -1e30f; l[r] = 0.f;
    }

    const int nchunks = (base + 31) / 64 + 1;
    for (int c = 0; c < nchunks; ++c) {
        const int key0 = c * 64;
        __syncthreads();
        // stage 64 keys of K (transposed) and V
        #pragma unroll
        for (int it = 0; it < 4; ++it) {
            int idx = tid + it * 256;        // 0..1023
            int j   = idx >> 4;
            int d4  = (idx & 15) << 2;
            const float4 k4 = *(const float4*)(kb + (size_t)(key0 + j) * (NKV * HD) + d4);
            Kt[d4 + 0][j] = k4.x; Kt[d4 + 1][j] = k4.y;
            Kt[d4 + 2][j] = k4.z; Kt[d4 + 3][j] = k4.w;
            *(float4*)&Vt[j][d4] = *(const float4*)(vb + (size_t)(key0 + j) * (NKV * HD) + d4);
        }
        __syncthreads();

        // scores: lane j holds s for key key0+j, 8 rows
        float s[8] = {0.f, 0.f, 0.f, 0.f, 0.f, 0.f, 0.f, 0.f};
        #pragma unroll 16
        for (int d = 0; d < 64; ++d) {
            float kd = Kt[d][lane];
            #pragma unroll
            for (int r = 0; r < 8; ++r)
                s[r] += lane_bcast(qreg[r], d) * kd;
        }

        // online softmax update per row
        float p[8], alpha[8];
        #pragma unroll
        for (int r = 0; r < 8; ++r) {
            float sr = s[r] * scale;
            if (key0 + lane > trow[r]) sr = -1e30f;
            float smax = wave_max64(sr);
            float mnew = fmaxf(m[r], smax);
            alpha[r] = __expf(m[r] - mnew);
            p[r]     = __expf(sr - mnew);
            l[r]     = l[r] * alpha[r] + wave_sum64(p[r]);
            m[r]     = mnew;
        }

        // output: lane d accumulates sum_j p[j] * V[j][d]
        float acc[8] = {0.f, 0.f, 0.f, 0.f, 0.f, 0.f, 0.f, 0.f};
        #pragma unroll 16
        for (int j = 0; j < 64; ++j) {
            float vj = Vt[j][lane];
            #pragma unroll
            for (int r = 0; r < 8; ++r)
                acc[r] += lane_bcast(p[r], j) * vj;
        }
        #pragma unroll
        for (int r = 0; r < 8; ++r)
            o[r] = o[r] * alpha[r] + acc[r];
    }

    #pragma unroll
    for (int r = 0; r < 8; ++r)
        y[((size_t)(b * T_ + trow[r]) * NH + h) * HD + lane] = o[r] / l[r];
}

// ---------------- launcher ----------------
extern "C" void kernel_launch(void* const* d_in, const int* in_sizes, int n_in,
                              void* d_out, int out_size, void* d_ws, size_t ws_size,
                              hipStream_t stream)
{
    const float* x    = (const float*)d_in[0];
    const float* cosT = (const float*)d_in[1];
    const float* sinT = (const float*)d_in[2];
    const float* Wq   = (const float*)d_in[3];
    const float* Wk   = (const float*)d_in[4];
    const float* Wv   = (const float*)d_in[5];
    const float* Wo   = (const float*)d_in[6];
    float* out = (float*)d_out;

    const int M = B_ * T_;  // 4096
    float* q = (float*)d_ws;                       // 4096*1024
    float* k = q + (size_t)M * NH  * HD;           // 4096*256
    float* v = k + (size_t)M * NKV * HD;           // 4096*256
    float* y = v + (size_t)M * NKV * HD;           // 4096*1024

    dim3 blk(256);
    // projections
    gemm_f32<<<dim3((NH  * HD) / 64, M / 64), blk, 0, stream>>>(x, Wq, q, M, NH  * HD, C_);
    gemm_f32<<<dim3((NKV * HD) / 64, M / 64), blk, 0, stream>>>(x, Wk, k, M, NKV * HD, C_);
    gemm_f32<<<dim3((NKV * HD) / 64, M / 64), blk, 0, stream>>>(x, Wv, v, M, NKV * HD, C_);
    // RoPE on q and k
    rope_kernel<<<(M * NH  * 32) / 256, blk, 0, stream>>>(q, cosT, sinT, NH,  M * NH  * 32);
    rope_kernel<<<(M * NKV * 32) / 256, blk, 0, stream>>>(k, cosT, sinT, NKV, M * NKV * 32);
    // attention
    attn_kernel<<<B_ * NH * (T_ / 32), blk, 0, stream>>>(q, k, v, y);
    // output projection
    gemm_f32<<<dim3(C_ / 64, M / 64), blk, 0, stream>>>(y, Wo, out, M, C_, C_);
}

// Round 2
// 604.890 us; speedup vs baseline: 2.6559x; 2.6559x over previous
//
#include <hip/hip_runtime.h>
#include <hip/hip_bf16.h>
#include <math.h>

#define NH   16
#define NKV  4
#define HD   64
#define B_   2
#define T_   2048
#define C_   1024

typedef __attribute__((ext_vector_type(8))) short short8;
typedef __attribute__((ext_vector_type(4))) float v4f;

__device__ inline ushort f2bf(float f) {
    union { float f; uint32_t u; } v; v.f = f;
    uint32_t r = v.u + 0x7fffu + ((v.u >> 16) & 1u);
    return (ushort)(r >> 16);
}
__device__ inline float bf2f(ushort u) {
    union { uint32_t u; float f; } v; v.u = ((uint32_t)u) << 16;
    return v.f;
}

// ---------------- fp32 tiled GEMM: C[M,N] = A[M,K] @ B[K,N], fp32 out ------
__global__ __launch_bounds__(256) void gemm_f32(
    const float* __restrict__ A, const float* __restrict__ Bm,
    float* __restrict__ C, int M, int N, int K)
{
    __shared__ __align__(16) float As[16][68];
    __shared__ __align__(16) float Bs[16][68];

    const int tid = threadIdx.x;
    const int tx = tid & 15;
    const int ty = tid >> 4;
    const int m0 = blockIdx.y * 64;
    const int n0 = blockIdx.x * 64;

    float acc[4][4] = {};

    for (int k0 = 0; k0 < K; k0 += 16) {
        {
            int m   = tid >> 2;
            int kk4 = (tid & 3) << 2;
            const float4 a4 = *(const float4*)(A + (size_t)(m0 + m) * K + k0 + kk4);
            As[kk4 + 0][m] = a4.x; As[kk4 + 1][m] = a4.y;
            As[kk4 + 2][m] = a4.z; As[kk4 + 3][m] = a4.w;
        }
        {
            int kk = tid >> 4;
            int n4 = (tid & 15) << 2;
            *(float4*)&Bs[kk][n4] = *(const float4*)(Bm + (size_t)(k0 + kk) * N + n0 + n4);
        }
        __syncthreads();
        #pragma unroll
        for (int kk = 0; kk < 16; ++kk) {
            const float4 a = *(const float4*)&As[kk][ty << 2];
            const float4 b = *(const float4*)&Bs[kk][tx << 2];
            const float av[4] = {a.x, a.y, a.z, a.w};
            const float bv[4] = {b.x, b.y, b.z, b.w};
            #pragma unroll
            for (int i = 0; i < 4; ++i)
                #pragma unroll
                for (int j = 0; j < 4; ++j)
                    acc[i][j] += av[i] * bv[j];
        }
        __syncthreads();
    }
    #pragma unroll
    for (int i = 0; i < 4; ++i) {
        float4 r = {acc[i][0], acc[i][1], acc[i][2], acc[i][3]};
        *(float4*)(C + (size_t)(m0 + (ty << 2) + i) * N + n0 + (tx << 2)) = r;
    }
}

// ---------------- same GEMM, bf16 output (for q,k,v) ----------------------
__global__ __launch_bounds__(256) void gemm_f32_bf16out(
    const float* __restrict__ A, const float* __restrict__ Bm,
    ushort* __restrict__ C, int M, int N, int K)
{
    __shared__ __align__(16) float As[16][68];
    __shared__ __align__(16) float Bs[16][68];

    const int tid = threadIdx.x;
    const int tx = tid & 15;
    const int ty = tid >> 4;
    const int m0 = blockIdx.y * 64;
    const int n0 = blockIdx.x * 64;

    float acc[4][4] = {};

    for (int k0 = 0; k0 < K; k0 += 16) {
        {
            int m   = tid >> 2;
            int kk4 = (tid & 3) << 2;
            const float4 a4 = *(const float4*)(A + (size_t)(m0 + m) * K + k0 + kk4);
            As[kk4 + 0][m] = a4.x; As[kk4 + 1][m] = a4.y;
            As[kk4 + 2][m] = a4.z; As[kk4 + 3][m] = a4.w;
        }
        {
            int kk = tid >> 4;
            int n4 = (tid & 15) << 2;
            *(float4*)&Bs[kk][n4] = *(const float4*)(Bm + (size_t)(k0 + kk) * N + n0 + n4);
        }
        __syncthreads();
        #pragma unroll
        for (int kk = 0; kk < 16; ++kk) {
            const float4 a = *(const float4*)&As[kk][ty << 2];
            const float4 b = *(const float4*)&Bs[kk][tx << 2];
            const float av[4] = {a.x, a.y, a.z, a.w};
            const float bv[4] = {b.x, b.y, b.z, b.w};
            #pragma unroll
            for (int i = 0; i < 4; ++i)
                #pragma unroll
                for (int j = 0; j < 4; ++j)
                    acc[i][j] += av[i] * bv[j];
        }
        __syncthreads();
    }
    #pragma unroll
    for (int i = 0; i < 4; ++i) {
        ushort4 r;
        r.x = f2bf(acc[i][0]); r.y = f2bf(acc[i][1]);
        r.z = f2bf(acc[i][2]); r.w = f2bf(acc[i][3]);
        *(ushort4*)(C + (size_t)(m0 + (ty << 2) + i) * N + n0 + (tx << 2)) = r;
    }
}

// ---------------- RoPE in-place on bf16 buffer [B*T, nh, 64] --------------
__global__ __launch_bounds__(256) void rope_bf16(
    ushort* __restrict__ p, const float* __restrict__ cs,
    const float* __restrict__ sn, int nh, int total)
{
    int i = blockIdx.x * 256 + threadIdx.x;
    if (i >= total) return;
    int d   = i & 31;
    int hh  = (i >> 5) % nh;
    int row = i / (32 * nh);
    int t   = row % T_;
    size_t base = (size_t)row * nh * HD + hh * HD + d;
    float x1 = bf2f(p[base]), x2 = bf2f(p[base + 32]);
    float c = cs[t * 32 + d], s = sn[t * 32 + d];
    p[base]      = f2bf(x1 * c - x2 * s);
    p[base + 32] = f2bf(x2 * c + x1 * s);
}

// ---------------- MFMA flash attention ------------------------------------
// qb: [B*T, NH, 64] bf16 (rope applied), kb/vb: [B*T, NKV, 64] bf16,
// y: [B*T, NH*64] fp32.
// Block = 4 waves, 64 q-rows; wave w owns rows q0+16w..+15. Keys in 64-chunks.
// LDS: Ks[key][d] (natural), Vt[d][key] (transposed), both 72-short rows
// (16B-aligned, worst 2-way bank alias = free). P per-wave [16][72] bf16.
#define LSTR 72
__global__ __launch_bounds__(256) void attn_mfma(
    const ushort* __restrict__ qb, const ushort* __restrict__ kb,
    const ushort* __restrict__ vb, float* __restrict__ y)
{
    __shared__ __align__(16) short Ks[64][LSTR];
    __shared__ __align__(16) short Vt[64][LSTR];
    __shared__ __align__(16) short Ps[4][16][LSTR];

    const int tid  = threadIdx.x;
    const int wid  = tid >> 6;
    const int ln   = tid & 63;
    const int l16  = ln & 15;
    const int quad = ln >> 4;

    const int tpb = T_ / 64;                     // 32 q-blocks per (b,h)
    const int blk = blockIdx.x;
    const int b   = blk / (NH * tpb);
    const int rem = blk % (NH * tpb);
    const int h   = rem / tpb;
    const int tb  = (tpb - 1) - (rem % tpb);     // heavy (long) blocks first
    const int q0  = tb * 64;
    const int kvh = h >> 2;

    const ushort* kptr = kb + ((size_t)(b * T_) * NKV + kvh) * HD;
    const ushort* vptr = vb + ((size_t)(b * T_) * NKV + kvh) * HD;

    // Q A-fragments straight from global: A[m=l16][k=quad*8+j], two K=32 halves
    short8 qf[2];
    {
        const ushort* qrow = qb + ((size_t)(b * T_ + q0 + wid * 16 + l16) * NH + h) * HD;
        qf[0] = *(const short8*)(qrow + quad * 8);
        qf[1] = *(const short8*)(qrow + 32 + quad * 8);
    }

    v4f oacc[4];
    float m[4], l[4];
    #pragma unroll
    for (int t = 0; t < 4; ++t) oacc[t] = (v4f){0.f, 0.f, 0.f, 0.f};
    #pragma unroll
    for (int r = 0; r < 4; ++r) { m[r] = -1e30f; l[r] = 0.f; }

    const int nch = q0 / 64 + 1;
    for (int c = 0; c < nch; ++c) {
        const int key0 = c * 64;
        __syncthreads();
        // stage K (natural) and V (transposed): 2 x ushort8 per thread each
        #pragma unroll
        for (int it = 0; it < 2; ++it) {
            int idx = tid + it * 256;
            int row = idx >> 3;             // key 0..63
            int col = (idx & 7) * 8;        // d
            short8 kv = *(const short8*)(kptr + (size_t)(key0 + row) * (NKV * HD) + col);
            *(short8*)&Ks[row][col] = kv;
            short8 vv = *(const short8*)(vptr + (size_t)(key0 + row) * (NKV * HD) + col);
            #pragma unroll
            for (int e = 0; e < 8; ++e) Vt[col + e][row] = vv[e];
        }
        __syncthreads();

        // S = Q @ K^T : 4 key-tiles x 2 K-halves
        v4f st[4];
        #pragma unroll
        for (int t = 0; t < 4; ++t) {
            short8 b0 = *(const short8*)&Ks[t * 16 + l16][quad * 8];
            short8 b1 = *(const short8*)&Ks[t * 16 + l16][32 + quad * 8];
            v4f s = (v4f){0.f, 0.f, 0.f, 0.f};
            s = __builtin_amdgcn_mfma_f32_16x16x32_bf16(qf[0], b0, s, 0, 0, 0);
            s = __builtin_amdgcn_mfma_f32_16x16x32_bf16(qf[1], b1, s, 0, 0, 0);
            st[t] = s;
        }

        // online softmax per row (C layout: row = quad*4+r, col = t*16+l16)
        #pragma unroll
        for (int r = 0; r < 4; ++r) {
            const int rowg = q0 + wid * 16 + quad * 4 + r;
            float sv[4];
            #pragma unroll
            for (int t = 0; t < 4; ++t) {
                float s = st[t][r] * 0.125f;
                int kg = key0 + t * 16 + l16;
                sv[t] = (kg <= rowg) ? s : -1e30f;
            }
            float mx = fmaxf(fmaxf(sv[0], sv[1]), fmaxf(sv[2], sv[3]));
            mx = fmaxf(mx, __shfl_xor(mx, 8, 64));
            mx = fmaxf(mx, __shfl_xor(mx, 4, 64));
            mx = fmaxf(mx, __shfl_xor(mx, 2, 64));
            mx = fmaxf(mx, __shfl_xor(mx, 1, 64));
            float mnew  = fmaxf(m[r], mx);
            float alpha = __expf(m[r] - mnew);
            m[r] = mnew;
            float sum = 0.f;
            float pv[4];
            #pragma unroll
            for (int t = 0; t < 4; ++t) {
                pv[t] = __expf(sv[t] - mnew);
                sum += pv[t];
            }
            sum += __shfl_xor(sum, 8, 64);
            sum += __shfl_xor(sum, 4, 64);
            sum += __shfl_xor(sum, 2, 64);
            sum += __shfl_xor(sum, 1, 64);
            l[r] = l[r] * alpha + sum;
            #pragma unroll
            for (int t = 0; t < 4; ++t) {
                oacc[t][r] *= alpha;
                Ps[wid][quad * 4 + r][t * 16 + l16] = (short)f2bf(pv[t]);
            }
        }

        // wave-private P region: only need this wave's ds_writes drained
        asm volatile("s_waitcnt lgkmcnt(0)" ::: "memory");

        // O += P @ V : A[m=l16][k], B from Vt[d][key]
        short8 pa0 = *(const short8*)&Ps[wid][l16][quad * 8];
        short8 pa1 = *(const short8*)&Ps[wid][l16][32 + quad * 8];
        #pragma unroll
        for (int t = 0; t < 4; ++t) {
            short8 v0 = *(const short8*)&Vt[t * 16 + l16][quad * 8];
            short8 v1 = *(const short8*)&Vt[t * 16 + l16][32 + quad * 8];
            oacc[t] = __builtin_amdgcn_mfma_f32_16x16x32_bf16(pa0, v0, oacc[t], 0, 0, 0);
            oacc[t] = __builtin_amdgcn_mfma_f32_16x16x32_bf16(pa1, v1, oacc[t], 0, 0, 0);
        }
    }

    // epilogue: y[row][h*64+d] = O / l
    #pragma unroll
    for (int r = 0; r < 4; ++r) {
        const int rowg = q0 + wid * 16 + quad * 4 + r;
        float inv = 1.0f / l[r];
        float* yrow = y + (size_t)(b * T_ + rowg) * (NH * HD) + h * HD;
        #pragma unroll
        for (int t = 0; t < 4; ++t)
            yrow[t * 16 + l16] = oacc[t][r] * inv;
    }
}

// ---------------- launcher ----------------
extern "C" void kernel_launch(void* const* d_in, const int* in_sizes, int n_in,
                              void* d_out, int out_size, void* d_ws, size_t ws_size,
                              hipStream_t stream)
{
    const float* x    = (const float*)d_in[0];
    const float* cosT = (const float*)d_in[1];
    const float* sinT = (const float*)d_in[2];
    const float* Wq   = (const float*)d_in[3];
    const float* Wk   = (const float*)d_in[4];
    const float* Wv   = (const float*)d_in[5];
    const float* Wo   = (const float*)d_in[6];
    float* out = (float*)d_out;

    const int M = B_ * T_;  // 4096
    float*  y    = (float*)d_ws;                         // 16 MB
    ushort* qbuf = (ushort*)(y + (size_t)M * C_);        // 8 MB
    ushort* kbuf = qbuf + (size_t)M * NH  * HD;          // 2 MB
    ushort* vbuf = kbuf + (size_t)M * NKV * HD;          // 2 MB

    dim3 blk(256);
    // projections (bf16 out)
    gemm_f32_bf16out<<<dim3((NH  * HD) / 64, M / 64), blk, 0, stream>>>(x, Wq, qbuf, M, NH  * HD, C_);
    gemm_f32_bf16out<<<dim3((NKV * HD) / 64, M / 64), blk, 0, stream>>>(x, Wk, kbuf, M, NKV * HD, C_);
    gemm_f32_bf16out<<<dim3((NKV * HD) / 64, M / 64), blk, 0, stream>>>(x, Wv, vbuf, M, NKV * HD, C_);
    // RoPE on q and k (in-place, bf16)
    rope_bf16<<<(M * NH  * 32) / 256, blk, 0, stream>>>(qbuf, cosT, sinT, NH,  M * NH  * 32);
    rope_bf16<<<(M * NKV * 32) / 256, blk, 0, stream>>>(kbuf, cosT, sinT, NKV, M * NKV * 32);
    // MFMA flash attention
    attn_mfma<<<B_ * NH * (T_ / 64), blk, 0, stream>>>(qbuf, kbuf, vbuf, y);
    // output projection (fp32)
    gemm_f32<<<dim3(C_ / 64, M / 64), blk, 0, stream>>>(y, Wo, out, M, C_, C_);
}

// Round 3
// 325.473 us; speedup vs baseline: 4.9360x; 1.8585x over previous
//
#include <hip/hip_runtime.h>
#include <hip/hip_bf16.h>
#include <math.h>

#define NH   16
#define NKV  4
#define HD   64
#define B_   2
#define T_   2048
#define C_   1024
#define QKVN 1536   // fused q(1024) | k(256) | v(256)

typedef __attribute__((ext_vector_type(8))) short short8;
typedef __attribute__((ext_vector_type(4))) float v4f;

__device__ inline ushort f2bf(float f) {
    union { float f; uint32_t u; } v; v.f = f;
    uint32_t r = v.u + 0x7fffu + ((v.u >> 16) & 1u);
    return (ushort)(r >> 16);
}
__device__ inline float bf2f(ushort u) {
    union { uint32_t u; float f; } v; v.u = ((uint32_t)u) << 16;
    return v.f;
}

// async global->LDS, 16B per lane; LDS dest must be wave-uniform base
__device__ inline void async16(const void* g, void* l) {
    __builtin_amdgcn_global_load_lds(
        (const __attribute__((address_space(1))) unsigned int*)g,
        (__attribute__((address_space(3))) unsigned int*)l, 16, 0, 0);
}

// ---------------- fp32 -> bf16 straight convert ---------------------------
__global__ __launch_bounds__(256) void f32_to_bf16(
    const float* __restrict__ in, ushort* __restrict__ out, int n)
{
    int i = (blockIdx.x * 256 + threadIdx.x) * 4;
    if (i >= n) return;
    float4 v = *(const float4*)(in + i);
    ushort4 o; o.x = f2bf(v.x); o.y = f2bf(v.y); o.z = f2bf(v.z); o.w = f2bf(v.w);
    *(ushort4*)(out + i) = o;
}

// ---------------- transpose + convert: W[1024,N] f32 -> WT[N][1024] bf16 ---
// 64x64 tiles; LDS stage; both global phases coalesced; LDS reads 2-way max.
__global__ __launch_bounds__(256) void transpose_f32_bf16(
    const float* __restrict__ W, ushort* __restrict__ WT, int N)
{
    __shared__ float tile[64][65];
    const int tid = threadIdx.x;
    const int k0 = blockIdx.y * 64, n0 = blockIdx.x * 64;
    #pragma unroll
    for (int it = 0; it < 4; ++it) {
        int r = (tid >> 4) + it * 16;
        int c = (tid & 15) * 4;
        float4 v = *(const float4*)(W + (size_t)(k0 + r) * N + n0 + c);
        tile[r][c] = v.x; tile[r][c + 1] = v.y; tile[r][c + 2] = v.z; tile[r][c + 3] = v.w;
    }
    __syncthreads();
    #pragma unroll
    for (int it = 0; it < 4; ++it) {
        int r = (tid >> 4) + it * 16;     // output row (= n)
        int c = (tid & 15) * 4;           // output col (= k)
        ushort4 o;
        o.x = f2bf(tile[c + 0][r]); o.y = f2bf(tile[c + 1][r]);
        o.z = f2bf(tile[c + 2][r]); o.w = f2bf(tile[c + 3][r]);
        *(ushort4*)(WT + (size_t)(n0 + r) * C_ + k0 + c) = o;
    }
}

// ---------------- bf16 MFMA GEMM: C[M,N] = A[M,K] @ Bt[N,K]^T --------------
// 128x128 tile, BK=32, 256 thr = 4 waves (2x2), each wave 64x64 = 4x4 mfma
// tiles of 16x16x32. Unpadded LDS rows (64B): fragment ds_read_b128 is
// 2-way bank-aliased = free; required contiguous for global_load_lds.
template <bool BF16OUT>
__global__ __launch_bounds__(256) void gemm_bf16bt(
    const ushort* __restrict__ A, const ushort* __restrict__ Bt,
    void* __restrict__ Cout, int M, int N, int K)
{
    __shared__ __align__(16) short As[128 * 32];
    __shared__ __align__(16) short Bs[128 * 32];

    const int tid  = threadIdx.x;
    const int lane = tid & 63;
    const int wid  = tid >> 6;
    const int l16  = lane & 15;
    const int quad = lane >> 4;
    const int wm   = wid >> 1, wn = wid & 1;
    const int m0   = blockIdx.y * 128;
    const int n0   = blockIdx.x * 128;

    v4f acc[4][4];
    #pragma unroll
    for (int i = 0; i < 4; ++i)
        #pragma unroll
        for (int j = 0; j < 4; ++j) acc[i][j] = (v4f){0.f, 0.f, 0.f, 0.f};

    for (int k0 = 0; k0 < K; k0 += 32) {
        __syncthreads();
        {
            // each wave stages 32 A-rows and 32 Bt-rows (16 rows / instr)
            const ushort* ag = A  + (size_t)(m0 + wid * 32 + (lane >> 2)) * K + k0 + (lane & 3) * 8;
            async16(ag,                 &As[(wid * 32) * 32]);
            async16(ag + (size_t)16 * K, &As[(wid * 32 + 16) * 32]);
            const ushort* bg = Bt + (size_t)(n0 + wid * 32 + (lane >> 2)) * K + k0 + (lane & 3) * 8;
            async16(bg,                 &Bs[(wid * 32) * 32]);
            async16(bg + (size_t)16 * K, &Bs[(wid * 32 + 16) * 32]);
        }
        __syncthreads();

        short8 af[4], bf[4];
        #pragma unroll
        for (int t = 0; t < 4; ++t) {
            af[t] = *(const short8*)&As[(wm * 64 + t * 16 + l16) * 32 + quad * 8];
            bf[t] = *(const short8*)&Bs[(wn * 64 + t * 16 + l16) * 32 + quad * 8];
        }
        #pragma unroll
        for (int i = 0; i < 4; ++i)
            #pragma unroll
            for (int j = 0; j < 4; ++j)
                acc[i][j] = __builtin_amdgcn_mfma_f32_16x16x32_bf16(af[i], bf[j], acc[i][j], 0, 0, 0);
    }

    // epilogue: C/D layout col=l16, row=quad*4+r
    #pragma unroll
    for (int i = 0; i < 4; ++i) {
        #pragma unroll
        for (int r = 0; r < 4; ++r) {
            const int row = m0 + wm * 64 + i * 16 + quad * 4 + r;
            #pragma unroll
            for (int j = 0; j < 4; ++j) {
                const int col = n0 + wn * 64 + j * 16 + l16;
                if (BF16OUT)
                    ((ushort*)Cout)[(size_t)row * N + col] = f2bf(acc[i][j][r]);
                else
                    ((float*)Cout)[(size_t)row * N + col] = acc[i][j][r];
            }
        }
    }
}

// ---------------- RoPE in-place on bf16 qkv buffer (row stride QKVN) ------
// p points at the first head's d=0 of the q- or k-section.
__global__ __launch_bounds__(256) void rope_bf16(
    ushort* __restrict__ p, const float* __restrict__ cs,
    const float* __restrict__ sn, int nh, int total)
{
    int i = blockIdx.x * 256 + threadIdx.x;
    if (i >= total) return;
    int d   = i & 31;
    int hh  = (i >> 5) % nh;
    int row = i / (32 * nh);
    int t   = row % T_;
    size_t base = (size_t)row * QKVN + hh * HD + d;
    float x1 = bf2f(p[base]), x2 = bf2f(p[base + 32]);
    float c = cs[t * 32 + d], s = sn[t * 32 + d];
    p[base]      = f2bf(x1 * c - x2 * s);
    p[base + 32] = f2bf(x2 * c + x1 * s);
}

// ---------------- MFMA flash attention ------------------------------------
// qkv: [B*T, 1536] bf16 (q|k|v fused, rope applied). y: [B*T, 1024] bf16.
#define LSTR 72
__global__ __launch_bounds__(256) void attn_mfma(
    const ushort* __restrict__ qkv, ushort* __restrict__ y)
{
    __shared__ __align__(16) short Ks[64][LSTR];
    __shared__ __align__(16) short Vt[64][LSTR];
    __shared__ __align__(16) short Ps[4][16][LSTR];

    const int tid  = threadIdx.x;
    const int wid  = tid >> 6;
    const int ln   = tid & 63;
    const int l16  = ln & 15;
    const int quad = ln >> 4;

    const int tpb = T_ / 64;
    const int blk = blockIdx.x;
    const int b   = blk / (NH * tpb);
    const int rem = blk % (NH * tpb);
    const int h   = rem / tpb;
    const int tb  = (tpb - 1) - (rem % tpb);     // heavy blocks first
    const int q0  = tb * 64;
    const int kvh = h >> 2;

    const ushort* kptr = qkv + (size_t)(b * T_) * QKVN + 1024 + kvh * HD;
    const ushort* vptr = qkv + (size_t)(b * T_) * QKVN + 1280 + kvh * HD;

    short8 qf[2];
    {
        const ushort* qrow = qkv + (size_t)(b * T_ + q0 + wid * 16 + l16) * QKVN + h * HD;
        qf[0] = *(const short8*)(qrow + quad * 8);
        qf[1] = *(const short8*)(qrow + 32 + quad * 8);
    }

    v4f oacc[4];
    float m[4], l[4];
    #pragma unroll
    for (int t = 0; t < 4; ++t) oacc[t] = (v4f){0.f, 0.f, 0.f, 0.f};
    #pragma unroll
    for (int r = 0; r < 4; ++r) { m[r] = -1e30f; l[r] = 0.f; }

    const int nch = q0 / 64 + 1;
    for (int c = 0; c < nch; ++c) {
        const int key0 = c * 64;
        __syncthreads();
        #pragma unroll
        for (int it = 0; it < 2; ++it) {
            int idx = tid + it * 256;
            int row = idx >> 3;
            int col = (idx & 7) * 8;
            short8 kv = *(const short8*)(kptr + (size_t)(key0 + row) * QKVN + col);
            *(short8*)&Ks[row][col] = kv;
            short8 vv = *(const short8*)(vptr + (size_t)(key0 + row) * QKVN + col);
            #pragma unroll
            for (int e = 0; e < 8; ++e) Vt[col + e][row] = vv[e];
        }
        __syncthreads();

        v4f st[4];
        #pragma unroll
        for (int t = 0; t < 4; ++t) {
            short8 b0 = *(const short8*)&Ks[t * 16 + l16][quad * 8];
            short8 b1 = *(const short8*)&Ks[t * 16 + l16][32 + quad * 8];
            v4f s = (v4f){0.f, 0.f, 0.f, 0.f};
            s = __builtin_amdgcn_mfma_f32_16x16x32_bf16(qf[0], b0, s, 0, 0, 0);
            s = __builtin_amdgcn_mfma_f32_16x16x32_bf16(qf[1], b1, s, 0, 0, 0);
            st[t] = s;
        }

        #pragma unroll
        for (int r = 0; r < 4; ++r) {
            const int rowg = q0 + wid * 16 + quad * 4 + r;
            float sv[4];
            #pragma unroll
            for (int t = 0; t < 4; ++t) {
                float s = st[t][r] * 0.125f;
                int kg = key0 + t * 16 + l16;
                sv[t] = (kg <= rowg) ? s : -1e30f;
            }
            float mx = fmaxf(fmaxf(sv[0], sv[1]), fmaxf(sv[2], sv[3]));
            mx = fmaxf(mx, __shfl_xor(mx, 8, 64));
            mx = fmaxf(mx, __shfl_xor(mx, 4, 64));
            mx = fmaxf(mx, __shfl_xor(mx, 2, 64));
            mx = fmaxf(mx, __shfl_xor(mx, 1, 64));
            float mnew  = fmaxf(m[r], mx);
            float alpha = __expf(m[r] - mnew);
            m[r] = mnew;
            float sum = 0.f;
            float pv[4];
            #pragma unroll
            for (int t = 0; t < 4; ++t) {
                pv[t] = __expf(sv[t] - mnew);
                sum += pv[t];
            }
            sum += __shfl_xor(sum, 8, 64);
            sum += __shfl_xor(sum, 4, 64);
            sum += __shfl_xor(sum, 2, 64);
            sum += __shfl_xor(sum, 1, 64);
            l[r] = l[r] * alpha + sum;
            #pragma unroll
            for (int t = 0; t < 4; ++t) {
                oacc[t][r] *= alpha;
                Ps[wid][quad * 4 + r][t * 16 + l16] = (short)f2bf(pv[t]);
            }
        }

        asm volatile("s_waitcnt lgkmcnt(0)" ::: "memory");

        short8 pa0 = *(const short8*)&Ps[wid][l16][quad * 8];
        short8 pa1 = *(const short8*)&Ps[wid][l16][32 + quad * 8];
        #pragma unroll
        for (int t = 0; t < 4; ++t) {
            short8 v0 = *(const short8*)&Vt[t * 16 + l16][quad * 8];
            short8 v1 = *(const short8*)&Vt[t * 16 + l16][32 + quad * 8];
            oacc[t] = __builtin_amdgcn_mfma_f32_16x16x32_bf16(pa0, v0, oacc[t], 0, 0, 0);
            oacc[t] = __builtin_amdgcn_mfma_f32_16x16x32_bf16(pa1, v1, oacc[t], 0, 0, 0);
        }
    }

    #pragma unroll
    for (int r = 0; r < 4; ++r) {
        const int rowg = q0 + wid * 16 + quad * 4 + r;
        float inv = 1.0f / l[r];
        ushort* yrow = y + (size_t)(b * T_ + rowg) * (NH * HD) + h * HD;
        #pragma unroll
        for (int t = 0; t < 4; ++t)
            yrow[t * 16 + l16] = f2bf(oacc[t][r] * inv);
    }
}

// ---------------- launcher ----------------
extern "C" void kernel_launch(void* const* d_in, const int* in_sizes, int n_in,
                              void* d_out, int out_size, void* d_ws, size_t ws_size,
                              hipStream_t stream)
{
    const float* x    = (const float*)d_in[0];
    const float* cosT = (const float*)d_in[1];
    const float* sinT = (const float*)d_in[2];
    const float* Wq   = (const float*)d_in[3];
    const float* Wk   = (const float*)d_in[4];
    const float* Wv   = (const float*)d_in[5];
    const float* Wo   = (const float*)d_in[6];
    float* out = (float*)d_out;

    const int M = B_ * T_;  // 4096
    ushort* xb     = (ushort*)d_ws;                       // 4096*1024
    ushort* qkv    = xb  + (size_t)M * C_;                // 4096*1536
    ushort* yb     = qkv + (size_t)M * QKVN;              // 4096*1024
    ushort* WqkvT  = yb  + (size_t)M * C_;                // 1536*1024
    ushort* WoT    = WqkvT + (size_t)QKVN * C_;           // 1024*1024

    dim3 blk(256);
    // converts + weight transposes
    f32_to_bf16<<<(M * C_ / 4) / 256, blk, 0, stream>>>(x, xb, M * C_);
    transpose_f32_bf16<<<dim3(16, 16), blk, 0, stream>>>(Wq, WqkvT, 1024);
    transpose_f32_bf16<<<dim3(4,  16), blk, 0, stream>>>(Wk, WqkvT + (size_t)1024 * C_, 256);
    transpose_f32_bf16<<<dim3(4,  16), blk, 0, stream>>>(Wv, WqkvT + (size_t)1280 * C_, 256);
    transpose_f32_bf16<<<dim3(16, 16), blk, 0, stream>>>(Wo, WoT, 1024);
    // fused QKV projection (bf16 out)
    gemm_bf16bt<true><<<dim3(QKVN / 128, M / 128), blk, 0, stream>>>(xb, WqkvT, qkv, M, QKVN, C_);
    // RoPE on q and k sections
    rope_bf16<<<(M * NH  * 32) / 256, blk, 0, stream>>>(qkv,        cosT, sinT, NH,  M * NH  * 32);
    rope_bf16<<<(M * NKV * 32) / 256, blk, 0, stream>>>(qkv + 1024, cosT, sinT, NKV, M * NKV * 32);
    // attention
    attn_mfma<<<B_ * NH * (T_ / 64), blk, 0, stream>>>(qkv, yb);
    // output projection (fp32 out)
    gemm_bf16bt<false><<<dim3(C_ / 128, M / 128), blk, 0, stream>>>(yb, WoT, out, M, C_, C_);
}